// Round 6
// baseline (1356.712 us; speedup 1.0000x reference)
//
#include <hip/hip_runtime.h>
#include <stdint.h>

#define NROWS 8192
#define DDIM  256
#define K2    512          // [hi | lo] packed per row
#define MARGIN_F 0.2f
#define MFMA16 __builtin_amdgcn_mfma_f32_16x16x32_bf16
#define SBAR0() __builtin_amdgcn_sched_barrier(0)

typedef short  short8  __attribute__((ext_vector_type(8)));
typedef float  floatx4 __attribute__((ext_vector_type(4)));

// Static device buffers (avoid depending on ws_size).
__device__ unsigned short gA[(size_t)NROWS * K2];   // im split: [hi | lo]
__device__ unsigned short gB[(size_t)NROWS * K2];   // s  split: [hi | lo]
__device__ float    g_diag[NROWS];
__device__ unsigned g_rowcnt[NROWS];
__device__ unsigned g_rowkey[NROWS];
__device__ unsigned g_colcnt[NROWS];
__device__ unsigned g_colkey[NROWS];
// Scrap sinks for the DIAGNOSTIC kernels (never read by finalize).
__device__ unsigned g_s1[NROWS], g_s2[NROWS], g_s3[NROWS], g_s4[NROWS];
__device__ float    g_scrapf[(size_t)512 * 512];

__device__ __forceinline__ unsigned short f2bf_rne(float x){
    unsigned u = __float_as_uint(x);
    return (unsigned short)((u + 0x7FFFu + ((u >> 16) & 1u)) >> 16);
}
__device__ __forceinline__ float bf2f(unsigned short h){
    return __uint_as_float(((unsigned)h) << 16);
}
// monotone float -> uint key (order-preserving), so atomicMax works on floats
__device__ __forceinline__ unsigned fkey(float f){
    unsigned u = __float_as_uint(f);
    return (u & 0x80000000u) ? ~u : (u | 0x80000000u);
}
__device__ __forceinline__ float kinv(unsigned k){
    unsigned u = (k & 0x80000000u) ? (k ^ 0x80000000u) : ~k;
    return __uint_as_float(u);
}

__device__ __forceinline__ void load_lds16(const unsigned short* gptr, void* lptr){
    __builtin_amdgcn_global_load_lds(
        (const __attribute__((address_space(1))) unsigned int*)(uintptr_t)gptr,
        (__attribute__((address_space(3))) unsigned int*)(unsigned)(uintptr_t)lptr,
        16, 0, 0);
}

// One wave per row: fp32 diag dot, hi/lo bf16 split, stats init.
__global__ __launch_bounds__(256) void prep_kernel(const float* __restrict__ im,
                                                   const float* __restrict__ s){
    const int w    = threadIdx.x >> 6;
    const int lane = threadIdx.x & 63;
    const int row  = blockIdx.x * 4 + w;

    const float4 a = ((const float4*)(im + (size_t)row * DDIM))[lane];
    const float4 b = ((const float4*)(s  + (size_t)row * DDIM))[lane];

    float dp = a.x*b.x + a.y*b.y + a.z*b.z + a.w*b.w;
    #pragma unroll
    for (int m = 1; m < 64; m <<= 1) dp += __shfl_xor(dp, m, 64);
    if (lane == 0){
        g_diag[row]   = dp;
        g_rowcnt[row] = 0u; g_rowkey[row] = 0u;
        g_colcnt[row] = 0u; g_colkey[row] = 0u;
    }

    float av[4] = {a.x, a.y, a.z, a.w};
    float bv[4] = {b.x, b.y, b.z, b.w};
    unsigned short ah[4], al[4], bh[4], bl[4];
    #pragma unroll
    for (int i = 0; i < 4; ++i){
        ah[i] = f2bf_rne(av[i]); al[i] = f2bf_rne(av[i] - bf2f(ah[i]));
        bh[i] = f2bf_rne(bv[i]); bl[i] = f2bf_rne(bv[i] - bf2f(bh[i]));
    }
    const size_t base = (size_t)row * K2 + lane * 4;
    *(ushort4*)&gA[base      ] = make_ushort4(ah[0], ah[1], ah[2], ah[3]);
    *(ushort4*)&gA[base + 256] = make_ushort4(al[0], al[1], al[2], al[3]);
    *(ushort4*)&gB[base      ] = make_ushort4(bh[0], bh[1], bh[2], bh[3]);
    *(ushort4*)&gB[base + 256] = make_ushort4(bl[0], bl[1], bl[2], bl[3]);
}

// Stage one 16KB unit (verified R13/R15: absmax 0, SQ_LDS_BANK_CONFLICT 0).
__device__ __forceinline__ void stage_unit256(const unsigned short* __restrict__ Obase,
                                              int c, int hl, unsigned short* sb, int tid){
    #pragma unroll
    for (int q2 = 0; q2 < 2; ++q2){
        const int o  = q2 * 8192 + tid * 16;    // dest byte in 16KB unit
        const int r  = o >> 6;                  // row 0..255 (64B rows)
        const int sp = (o >> 4) & 3;            // physical slot
        const int ql = sp ^ ((r >> 1) & 3);     // logical k-slot
        const size_t goff = (size_t)r * K2 + (size_t)c * 32 + (size_t)hl * 256 + (size_t)ql * 8;
        load_lds16(Obase + goff, (char*)sb + o);
    }
}

// ---- phase helpers ----
#define MFQ(A4, B4, MB) { \
    _Pragma("unroll") \
    for (int i_ = 0; i_ < 4; ++i_){ \
        _Pragma("unroll") \
        for (int nj_ = 0; nj_ < 4; ++nj_) \
            acc[(MB) + i_][nj_] = MFMA16((A4)[i_], (B4)[nj_], acc[(MB) + i_][nj_], 0, 0, 0); \
    } }
#define LDA4(U_, F_, MB) { \
    _Pragma("unroll") \
    for (int i_ = 0; i_ < 4; ++i_) \
        (F_)[i_] = *(const short8*)((const char*)(U_) + aoff + ((MB) + i_) * 1024); }
#define LDB4(U_, F_) { \
    _Pragma("unroll") \
    for (int nj_ = 0; nj_ < 4; ++nj_) \
        (F_)[nj_] = *(const short8*)((const char*)(U_) + boff + nj_ * 1024); }
#define LGKM0() { asm volatile("s_waitcnt lgkmcnt(0)" ::: "memory"); SBAR0(); }
#define BARR()  { SBAR0(); __builtin_amdgcn_s_barrier(); SBAR0(); }

// ===================== REAL KERNEL — identical to R15 ======================
__global__ __launch_bounds__(512, 2) void gemm_stats_kernel(){
    __shared__ unsigned short U[8][256 * 32];   // [0+d]=Ah, [2+d]=Bh, [4+d]=Al, [6+d]=Bl

    const int tid = threadIdx.x;
    const int bid = blockIdx.x;
    const int bi  = (bid & 7) * 4 + ((bid >> 3) & 3);
    const int bj  = bid >> 5;

    const int w    = tid >> 6, lane = tid & 63;
    const int quad = lane >> 4, l16 = lane & 15;
    const int wr   = w >> 2,   wc  = w & 3;
    const int sel  = (quad ^ ((l16 >> 1) & 3)) << 4;
    const int aoff = (wr * 128 + l16) * 64 + sel;
    const int boff = (wc * 64  + l16) * 64 + sel;

    floatx4 acc[8][4] = {};

    const unsigned short* Abase = gA + (size_t)bi * 256 * K2;
    const unsigned short* Bbase = gB + (size_t)bj * 256 * K2;

    stage_unit256(Abase, 0, 0, U[0], tid);
    stage_unit256(Bbase, 0, 0, U[2], tid);
    stage_unit256(Abase, 0, 1, U[4], tid);
    stage_unit256(Bbase, 0, 1, U[6], tid);
    SBAR0();
    asm volatile("s_waitcnt vmcnt(4)" ::: "memory");
    BARR();

    #pragma unroll 1
    for (int kc = 0; kc < 7; ++kc){
        const int d = kc & 1, e = d ^ 1;
        short8 ah[8], bh[4];
        stage_unit256(Abase, kc + 1, 0, U[0 + e], tid);
        SBAR0();
        LDA4(U[0 + d], &ah[0], 0); LDB4(U[2 + d], bh);
        LGKM0();
        __builtin_amdgcn_s_setprio(1); MFQ(&ah[0], bh, 0); __builtin_amdgcn_s_setprio(0);
        BARR();
        stage_unit256(Bbase, kc + 1, 0, U[2 + e], tid);
        SBAR0();
        LDA4(U[0 + d], &ah[4], 4);
        LGKM0();
        __builtin_amdgcn_s_setprio(1); MFQ(&ah[4], bh, 4); __builtin_amdgcn_s_setprio(0);
        SBAR0();
        asm volatile("s_waitcnt vmcnt(6)" ::: "memory");
        BARR();
        {
            stage_unit256(Abase, kc + 1, 1, U[4 + e], tid);
            SBAR0();
            short8 al0[4]; LDA4(U[4 + d], al0, 0);
            LGKM0();
            __builtin_amdgcn_s_setprio(1); MFQ(al0, bh, 0); __builtin_amdgcn_s_setprio(0);
            BARR();
        }
        {
            short8 al1[4]; LDA4(U[4 + d], al1, 4);
            LGKM0();
            __builtin_amdgcn_s_setprio(1); MFQ(al1, bh, 4); __builtin_amdgcn_s_setprio(0);
            SBAR0();
            asm volatile("s_waitcnt vmcnt(6)" ::: "memory");
            BARR();
        }
        {
            stage_unit256(Bbase, kc + 1, 1, U[6 + e], tid);
            SBAR0();
            short8 bl[4]; LDB4(U[6 + d], bl);
            LGKM0();
            __builtin_amdgcn_s_setprio(1); MFQ(&ah[0], bl, 0); __builtin_amdgcn_s_setprio(0);
            BARR();
            __builtin_amdgcn_s_setprio(1); MFQ(&ah[4], bl, 4); __builtin_amdgcn_s_setprio(0);
            SBAR0();
            asm volatile("s_waitcnt vmcnt(4)" ::: "memory");
            BARR();
        }
    }
    {
        short8 ah[8], bh[4];
        LDA4(U[1], &ah[0], 0); LDB4(U[3], bh);
        LGKM0();
        __builtin_amdgcn_s_setprio(1); MFQ(&ah[0], bh, 0); __builtin_amdgcn_s_setprio(0);
        BARR();
        LDA4(U[1], &ah[4], 4);
        LGKM0();
        __builtin_amdgcn_s_setprio(1); MFQ(&ah[4], bh, 4); __builtin_amdgcn_s_setprio(0);
        SBAR0();
        asm volatile("s_waitcnt vmcnt(2)" ::: "memory");
        BARR();
        {
            short8 al0[4]; LDA4(U[5], al0, 0);
            LGKM0();
            __builtin_amdgcn_s_setprio(1); MFQ(al0, bh, 0); __builtin_amdgcn_s_setprio(0);
            BARR();
        }
        {
            short8 al1[4]; LDA4(U[5], al1, 4);
            LGKM0();
            __builtin_amdgcn_s_setprio(1); MFQ(al1, bh, 4); __builtin_amdgcn_s_setprio(0);
            SBAR0();
            asm volatile("s_waitcnt vmcnt(0)" ::: "memory");
            BARR();
        }
        {
            short8 bl[4]; LDB4(U[7], bl);
            LGKM0();
            __builtin_amdgcn_s_setprio(1); MFQ(&ah[0], bl, 0); MFQ(&ah[4], bl, 4); __builtin_amdgcn_s_setprio(0);
        }
    }

    // ---- fused stats epilogue ----
    const int rowbase = bi * 256 + wr * 128;
    const int colbase = bj * 256 + wc * 64;

    #pragma unroll
    for (int mi = 0; mi < 8; ++mi){
        #pragma unroll
        for (int r = 0; r < 4; ++r){
            const int gi = rowbase + mi * 16 + quad * 4 + r;
            const float dv = g_diag[gi];
            int cnt = 0; float mx = -3.0e38f;
            #pragma unroll
            for (int nj = 0; nj < 4; ++nj){
                const float v  = acc[mi][nj][r];
                const int   gj = colbase + nj * 16 + l16;
                if (gi != gj){
                    cnt += (v < dv) ? 1 : 0;
                    mx = fmaxf(mx, v);
                }
            }
            #pragma unroll
            for (int m = 1; m < 16; m <<= 1){
                cnt += __shfl_xor(cnt, m, 64);
                mx   = fmaxf(mx, __shfl_xor(mx, m, 64));
            }
            if (l16 == 0){
                atomicAdd(&g_rowcnt[gi], (unsigned)cnt);
                atomicMax(&g_rowkey[gi], fkey(mx));
            }
        }
    }
    #pragma unroll
    for (int nj = 0; nj < 4; ++nj){
        const int gj = colbase + nj * 16 + l16;
        const float dv = g_diag[gj];
        int cnt = 0; float mx = -3.0e38f;
        #pragma unroll
        for (int mi = 0; mi < 8; ++mi){
            #pragma unroll
            for (int r = 0; r < 4; ++r){
                const float v  = acc[mi][nj][r];
                const int   gi = rowbase + mi * 16 + quad * 4 + r;
                if (gi != gj){
                    cnt += (v < dv) ? 1 : 0;
                    mx = fmaxf(mx, v);
                }
            }
        }
        #pragma unroll
        for (int m = 16; m < 64; m <<= 1){
            cnt += __shfl_xor(cnt, m, 64);
            mx   = fmaxf(mx, __shfl_xor(mx, m, 64));
        }
        if (quad == 0){
            atomicAdd(&g_colcnt[gj], (unsigned)cnt);
            atomicMax(&g_colkey[gj], fkey(mx));
        }
    }
}

// ================== DIAGNOSTIC ABLATIONS (scrap output only) ==================
// MODE 0 = noDMA   (staging removed; ds_read+MFMA+waits+barriers+epilogue kept)
// MODE 1 = noCompute (staging+vmcnt+barriers kept; ds_read/MFMA removed)
// MODE 2 = full K-loop, trivial epilogue (isolates epilogue cost by subtraction)
// REP repeats the K-loop so each dispatch ≈ 8 round-equivalents of the
// component -> surfaces above the real kernel's 184us in the top-k table iff
// the component >= ~23us/round. Output goes only to g_s*/g_scrapf.
template<int MODE, int REP>
__global__ __launch_bounds__(512, 2) void abl_kernel(){
    __shared__ unsigned short U[8][256 * 32];

    const int tid = threadIdx.x;
    const int bid = blockIdx.x;
    const int bi  = (bid & 7) * 4 + ((bid >> 3) & 3);
    const int bj  = bid >> 5;

    const int w    = tid >> 6, lane = tid & 63;
    const int quad = lane >> 4, l16 = lane & 15;
    const int wr   = w >> 2,   wc  = w & 3;
    const int sel  = (quad ^ ((l16 >> 1) & 3)) << 4;
    const int aoff = (wr * 128 + l16) * 64 + sel;
    const int boff = (wc * 64  + l16) * 64 + sel;

    floatx4 acc[8][4] = {};

    const unsigned short* Abase = gA + (size_t)bi * 256 * K2;
    const unsigned short* Bbase = gB + (size_t)bj * 256 * K2;

    #pragma unroll 1
    for (int rep = 0; rep < REP; ++rep){
        if constexpr (MODE != 0){
            stage_unit256(Abase, 0, 0, U[0], tid);
            stage_unit256(Bbase, 0, 0, U[2], tid);
            stage_unit256(Abase, 0, 1, U[4], tid);
            stage_unit256(Bbase, 0, 1, U[6], tid);
        }
        SBAR0();
        asm volatile("s_waitcnt vmcnt(4)" ::: "memory");
        BARR();

        #pragma unroll 1
        for (int kc = 0; kc < 7; ++kc){
            const int d = kc & 1, e = d ^ 1;
            short8 ah[8], bh[4];
            if constexpr (MODE != 0) stage_unit256(Abase, kc + 1, 0, U[0 + e], tid);
            SBAR0();
            if constexpr (MODE != 1){
                LDA4(U[0 + d], &ah[0], 0); LDB4(U[2 + d], bh);
                LGKM0();
                __builtin_amdgcn_s_setprio(1); MFQ(&ah[0], bh, 0); __builtin_amdgcn_s_setprio(0);
            }
            BARR();
            if constexpr (MODE != 0) stage_unit256(Bbase, kc + 1, 0, U[2 + e], tid);
            SBAR0();
            if constexpr (MODE != 1){
                LDA4(U[0 + d], &ah[4], 4);
                LGKM0();
                __builtin_amdgcn_s_setprio(1); MFQ(&ah[4], bh, 4); __builtin_amdgcn_s_setprio(0);
            }
            SBAR0();
            asm volatile("s_waitcnt vmcnt(6)" ::: "memory");
            BARR();
            if constexpr (MODE != 0) stage_unit256(Abase, kc + 1, 1, U[4 + e], tid);
            SBAR0();
            if constexpr (MODE != 1){
                short8 al0[4]; LDA4(U[4 + d], al0, 0);
                LGKM0();
                __builtin_amdgcn_s_setprio(1); MFQ(al0, bh, 0); __builtin_amdgcn_s_setprio(0);
            }
            BARR();
            if constexpr (MODE != 1){
                short8 al1[4]; LDA4(U[4 + d], al1, 4);
                LGKM0();
                __builtin_amdgcn_s_setprio(1); MFQ(al1, bh, 4); __builtin_amdgcn_s_setprio(0);
            }
            SBAR0();
            asm volatile("s_waitcnt vmcnt(6)" ::: "memory");
            BARR();
            if constexpr (MODE != 0) stage_unit256(Bbase, kc + 1, 1, U[6 + e], tid);
            SBAR0();
            if constexpr (MODE != 1){
                short8 bl[4]; LDB4(U[6 + d], bl);
                LGKM0();
                __builtin_amdgcn_s_setprio(1); MFQ(&ah[0], bl, 0); __builtin_amdgcn_s_setprio(0);
                BARR();
                __builtin_amdgcn_s_setprio(1); MFQ(&ah[4], bl, 4); __builtin_amdgcn_s_setprio(0);
            } else {
                BARR();
            }
            SBAR0();
            asm volatile("s_waitcnt vmcnt(4)" ::: "memory");
            BARR();
        }
        // tail chunk (kc=7, d=1)
        {
            short8 ah[8], bh[4];
            if constexpr (MODE != 1){
                LDA4(U[1], &ah[0], 0); LDB4(U[3], bh);
                LGKM0();
                __builtin_amdgcn_s_setprio(1); MFQ(&ah[0], bh, 0); __builtin_amdgcn_s_setprio(0);
            }
            BARR();
            if constexpr (MODE != 1){
                LDA4(U[1], &ah[4], 4);
                LGKM0();
                __builtin_amdgcn_s_setprio(1); MFQ(&ah[4], bh, 4); __builtin_amdgcn_s_setprio(0);
            }
            SBAR0();
            asm volatile("s_waitcnt vmcnt(2)" ::: "memory");
            BARR();
            if constexpr (MODE != 1){
                short8 al0[4]; LDA4(U[5], al0, 0);
                LGKM0();
                __builtin_amdgcn_s_setprio(1); MFQ(al0, bh, 0); __builtin_amdgcn_s_setprio(0);
            }
            BARR();
            if constexpr (MODE != 1){
                short8 al1[4]; LDA4(U[5], al1, 4);
                LGKM0();
                __builtin_amdgcn_s_setprio(1); MFQ(al1, bh, 4); __builtin_amdgcn_s_setprio(0);
            }
            SBAR0();
            asm volatile("s_waitcnt vmcnt(0)" ::: "memory");
            BARR();
            if constexpr (MODE != 1){
                short8 bl[4]; LDB4(U[7], bl);
                LGKM0();
                __builtin_amdgcn_s_setprio(1); MFQ(&ah[0], bl, 0); MFQ(&ah[4], bl, 4); __builtin_amdgcn_s_setprio(0);
            }
        }
        BARR();
    }

    if constexpr (MODE == 2){
        // trivial epilogue: per-lane sum keeps every MFMA live (rule #17)
        float s = 0.0f;
        #pragma unroll
        for (int mi = 0; mi < 8; ++mi)
            #pragma unroll
            for (int nj = 0; nj < 4; ++nj)
                #pragma unroll
                for (int r = 0; r < 4; ++r) s += acc[mi][nj][r];
        g_scrapf[(size_t)bid * 512 + tid] = s;
    } else {
        // full epilogue shape, atomics to scrap arrays
        const int rowbase = bi * 256 + wr * 128;
        const int colbase = bj * 256 + wc * 64;
        #pragma unroll
        for (int mi = 0; mi < 8; ++mi){
            #pragma unroll
            for (int r = 0; r < 4; ++r){
                const int gi = rowbase + mi * 16 + quad * 4 + r;
                const float dv = g_diag[gi];
                int cnt = 0; float mx = -3.0e38f;
                #pragma unroll
                for (int nj = 0; nj < 4; ++nj){
                    const float v  = acc[mi][nj][r];
                    const int   gj = colbase + nj * 16 + l16;
                    if (gi != gj){ cnt += (v < dv) ? 1 : 0; mx = fmaxf(mx, v); }
                }
                #pragma unroll
                for (int m = 1; m < 16; m <<= 1){
                    cnt += __shfl_xor(cnt, m, 64);
                    mx   = fmaxf(mx, __shfl_xor(mx, m, 64));
                }
                if (l16 == 0){
                    atomicAdd(&g_s1[gi], (unsigned)cnt);
                    atomicMax(&g_s2[gi], fkey(mx));
                }
            }
        }
        #pragma unroll
        for (int nj = 0; nj < 4; ++nj){
            const int gj = colbase + nj * 16 + l16;
            const float dv = g_diag[gj];
            int cnt = 0; float mx = -3.0e38f;
            #pragma unroll
            for (int mi = 0; mi < 8; ++mi){
                #pragma unroll
                for (int r = 0; r < 4; ++r){
                    const float v  = acc[mi][nj][r];
                    const int   gi = rowbase + mi * 16 + quad * 4 + r;
                    if (gi != gj){ cnt += (v < dv) ? 1 : 0; mx = fmaxf(mx, v); }
                }
            }
            #pragma unroll
            for (int m = 16; m < 64; m <<= 1){
                cnt += __shfl_xor(cnt, m, 64);
                mx   = fmaxf(mx, __shfl_xor(mx, m, 64));
            }
            if (quad == 0){
                atomicAdd(&g_s3[gj], (unsigned)cnt);
                atomicMax(&g_s4[gj], fkey(mx));
            }
        }
    }
}

// Pure MFMA floor: 768 MFMAs/wave/rep from registers, no memory in loop.
template<int REP>
__global__ __launch_bounds__(512, 2) void abl_mfmaonly(){
    __shared__ unsigned short U[8][256 * 32];   // keep LDS footprint = same occupancy
    U[0][threadIdx.x] = (unsigned short)threadIdx.x;
    __syncthreads();

    const int lane = threadIdx.x & 63;
    short8 af[8], bf4[4];
    #pragma unroll
    for (int i = 0; i < 8; ++i)
        #pragma unroll
        for (int e = 0; e < 8; ++e) af[i][e] = (short)(lane * 8 + i + e);
    #pragma unroll
    for (int j = 0; j < 4; ++j)
        #pragma unroll
        for (int e = 0; e < 8; ++e) bf4[j][e] = (short)(lane + j * 3 + e);

    floatx4 acc[8][4] = {};
    #pragma unroll 1
    for (int rep = 0; rep < REP; ++rep){
        #pragma unroll 1
        for (int kc = 0; kc < 8; ++kc){
            __builtin_amdgcn_s_setprio(1);
            MFQ(&af[0], bf4, 0); MFQ(&af[4], bf4, 4);   // pass1
            MFQ(&af[0], bf4, 0); MFQ(&af[4], bf4, 4);   // pass2
            MFQ(&af[0], bf4, 0); MFQ(&af[4], bf4, 4);   // pass3
            __builtin_amdgcn_s_setprio(0);
        }
    }
    float s = 0.0f;
    #pragma unroll
    for (int mi = 0; mi < 8; ++mi)
        #pragma unroll
        for (int nj = 0; nj < 4; ++nj)
            #pragma unroll
            for (int r = 0; r < 4; ++r) s += acc[mi][nj][r];
    g_scrapf[(size_t)blockIdx.x * 512 + threadIdx.x] = s;
}

__global__ __launch_bounds__(256) void finalize_kernel(float* __restrict__ out){
    __shared__ double red[256];
    double acc = 0.0;
    #pragma unroll
    for (int it = 0; it < NROWS / 256; ++it){
        const int i = it * 256 + threadIdx.x;
        const float d  = g_diag[i];
        const float cs  = fmaxf(MARGIN_F + kinv(g_rowkey[i]) - d, 0.0f) * (1.0f / (float)(g_rowcnt[i] + 1u));
        const float cim = fmaxf(MARGIN_F + kinv(g_colkey[i]) - d, 0.0f) * (1.0f / (float)(g_colcnt[i] + 1u));
        acc += (double)cs + (double)cim;
    }
    red[threadIdx.x] = acc;
    __syncthreads();
    for (int s2 = 128; s2 > 0; s2 >>= 1){
        if (threadIdx.x < s2) red[threadIdx.x] += red[threadIdx.x + s2];
        __syncthreads();
    }
    if (threadIdx.x == 0) out[0] = (float)red[0];
}

extern "C" void kernel_launch(void* const* d_in, const int* in_sizes, int n_in,
                              void* d_out, int out_size, void* d_ws, size_t ws_size,
                              hipStream_t stream){
    const float* im = (const float*)d_in[0];
    const float* s  = (const float*)d_in[1];
    float* out = (float*)d_out;

    // real pipeline (unchanged R15 path; output exact)
    prep_kernel<<<NROWS / 4, 256, 0, stream>>>(im, s);
    gemm_stats_kernel<<<1024, 512, 0, stream>>>();
    finalize_kernel<<<1, 256, 0, stream>>>(out);

    // diagnostics AFTER finalize: touch only scrap buffers.
    // grid 512 (2 rounds/CU) x REP=4 = 8 round-equivalents per dispatch.
    abl_kernel<0, 4><<<512, 512, 0, stream>>>();   // noDMA: compute side only
    abl_kernel<1, 4><<<512, 512, 0, stream>>>();   // noCompute: DMA+barriers only
    abl_kernel<2, 4><<<512, 512, 0, stream>>>();   // full loop, trivial epilogue
    abl_mfmaonly<32><<<512, 512, 0, stream>>>();   // pure MFMA floor
}

// Round 7
// 253.047 us; speedup vs baseline: 5.3615x; 5.3615x over previous
//
#include <hip/hip_runtime.h>
#include <stdint.h>

#define NROWS 8192
#define DDIM  256
#define K2    512          // [hi | lo] packed per row
#define MARGIN_F 0.2f
#define MFMA16 __builtin_amdgcn_mfma_f32_16x16x32_bf16
#define SBAR0() __builtin_amdgcn_sched_barrier(0)

typedef short  short8  __attribute__((ext_vector_type(8)));
typedef float  floatx4 __attribute__((ext_vector_type(4)));

// Static device buffers (avoid depending on ws_size).
__device__ unsigned short gA[(size_t)NROWS * K2];   // im split: [hi | lo]
__device__ unsigned short gB[(size_t)NROWS * K2];   // s  split: [hi | lo]
__device__ float    g_diag[NROWS];
__device__ unsigned g_rowcnt[NROWS];
__device__ unsigned g_rowkey[NROWS];
__device__ unsigned g_colcnt[NROWS];
__device__ unsigned g_colkey[NROWS];

__device__ __forceinline__ unsigned short f2bf_rne(float x){
    unsigned u = __float_as_uint(x);
    return (unsigned short)((u + 0x7FFFu + ((u >> 16) & 1u)) >> 16);
}
__device__ __forceinline__ float bf2f(unsigned short h){
    return __uint_as_float(((unsigned)h) << 16);
}
// monotone float -> uint key (order-preserving), so atomicMax works on floats
__device__ __forceinline__ unsigned fkey(float f){
    unsigned u = __float_as_uint(f);
    return (u & 0x80000000u) ? ~u : (u | 0x80000000u);
}
__device__ __forceinline__ float kinv(unsigned k){
    unsigned u = (k & 0x80000000u) ? (k ^ 0x80000000u) : ~k;
    return __uint_as_float(u);
}

__device__ __forceinline__ void load_lds16(const unsigned short* gptr, void* lptr){
    __builtin_amdgcn_global_load_lds(
        (const __attribute__((address_space(1))) unsigned int*)(uintptr_t)gptr,
        (__attribute__((address_space(3))) unsigned int*)(unsigned)(uintptr_t)lptr,
        16, 0, 0);
}

// One wave per row: fp32 diag dot, hi/lo bf16 split, stats init.
__global__ __launch_bounds__(256) void prep_kernel(const float* __restrict__ im,
                                                   const float* __restrict__ s){
    const int w    = threadIdx.x >> 6;
    const int lane = threadIdx.x & 63;
    const int row  = blockIdx.x * 4 + w;

    const float4 a = ((const float4*)(im + (size_t)row * DDIM))[lane];
    const float4 b = ((const float4*)(s  + (size_t)row * DDIM))[lane];

    float dp = a.x*b.x + a.y*b.y + a.z*b.z + a.w*b.w;
    #pragma unroll
    for (int m = 1; m < 64; m <<= 1) dp += __shfl_xor(dp, m, 64);
    if (lane == 0){
        g_diag[row]   = dp;
        g_rowcnt[row] = 0u; g_rowkey[row] = 0u;
        g_colcnt[row] = 0u; g_colkey[row] = 0u;
    }

    float av[4] = {a.x, a.y, a.z, a.w};
    float bv[4] = {b.x, b.y, b.z, b.w};
    unsigned short ah[4], al[4], bh[4], bl[4];
    #pragma unroll
    for (int i = 0; i < 4; ++i){
        ah[i] = f2bf_rne(av[i]); al[i] = f2bf_rne(av[i] - bf2f(ah[i]));
        bh[i] = f2bf_rne(bv[i]); bl[i] = f2bf_rne(bv[i] - bf2f(bh[i]));
    }
    const size_t base = (size_t)row * K2 + lane * 4;
    *(ushort4*)&gA[base      ] = make_ushort4(ah[0], ah[1], ah[2], ah[3]);
    *(ushort4*)&gA[base + 256] = make_ushort4(al[0], al[1], al[2], al[3]);
    *(ushort4*)&gB[base      ] = make_ushort4(bh[0], bh[1], bh[2], bh[3]);
    *(ushort4*)&gB[base + 256] = make_ushort4(bl[0], bl[1], bl[2], bl[3]);
}

// Stage one 16KB unit (verified R13/R15: absmax 0, SQ_LDS_BANK_CONFLICT 0).
__device__ __forceinline__ void stage_unit256(const unsigned short* __restrict__ Obase,
                                              int c, int hl, unsigned short* sb, int tid){
    #pragma unroll
    for (int q2 = 0; q2 < 2; ++q2){
        const int o  = q2 * 8192 + tid * 16;    // dest byte in 16KB unit
        const int r  = o >> 6;                  // row 0..255 (64B rows)
        const int sp = (o >> 4) & 3;            // physical slot
        const int ql = sp ^ ((r >> 1) & 3);     // logical k-slot
        const size_t goff = (size_t)r * K2 + (size_t)c * 32 + (size_t)hl * 256 + (size_t)ql * 8;
        load_lds16(Obase + goff, (char*)sb + o);
    }
}

// ---- compute helpers (identical math/order to R15) ----
#define MFQ(A4, B4, MB) { \
    _Pragma("unroll") \
    for (int i_ = 0; i_ < 4; ++i_){ \
        _Pragma("unroll") \
        for (int nj_ = 0; nj_ < 4; ++nj_) \
            acc[(MB) + i_][nj_] = MFMA16((A4)[i_], (B4)[nj_], acc[(MB) + i_][nj_], 0, 0, 0); \
    } }
#define LDA4(U_, F_, MB) { \
    _Pragma("unroll") \
    for (int i_ = 0; i_ < 4; ++i_) \
        (F_)[i_] = *(const short8*)((const char*)(U_) + aoff + ((MB) + i_) * 1024); }
#define LDB4(U_, F_) { \
    _Pragma("unroll") \
    for (int nj_ = 0; nj_ < 4; ++nj_) \
        (F_)[nj_] = *(const short8*)((const char*)(U_) + boff + nj_ * 1024); }

// 256x256 tile, 8 waves (2Mx4N, 128x64/wave), 16x16x32 bf16, 3-pass hi/lo.
// R17 vs R15: ablation (R16) proved the MFMA floor is ~42us and that THIS
// structure (512thr/128KB LDS/setprio, no barriers) reaches 93% of peak —
// so R15's 140us of idle lives in the 96-barrier-per-block lockstep skeleton
// (2300 cyc/phase vs ~900 of content; R13/R15 sustain only 4.7 B/cyc/CU VMEM
// vs 9.2/12.9 demonstrated by R12/R14 -> not VMEM-throughput-bound).
// New chunk skeleton (m201-style depth, 2 barriers/chunk, 16/block total):
//   barrier_A   (all waves done reading buf[e] = chunk c-1 data)
//   issue ALL 4 units of chunk c+1 into buf[e]   (8 DMA ops/thread)
//   s_waitcnt vmcnt(8)   (retires exactly chunk c's 8 ops, issued a full
//                         chunk earlier; tail: vmcnt(0))
//   barrier_B   (publish chunk c's LDS)
//   6 compute phases (P1a..P3b), NO barriers, compiler-managed lgkmcnt.
// Accumulation order per element unchanged (kc 0..7, pass1->2->3) => absmax 0.
__global__ __launch_bounds__(512, 2) void gemm_stats_kernel(){
    __shared__ unsigned short U[8][256 * 32];   // [0+d]=Ah, [2+d]=Bh, [4+d]=Al, [6+d]=Bl

    const int tid = threadIdx.x;
    const int bid = blockIdx.x;
    // bid[2:0]->XCD band of bi, bid[4:3]->bi within band, bid[9:5]->bj
    const int bi  = (bid & 7) * 4 + ((bid >> 3) & 3);
    const int bj  = bid >> 5;

    const int w    = tid >> 6, lane = tid & 63;
    const int quad = lane >> 4, l16 = lane & 15;
    const int wr   = w >> 2,   wc  = w & 3;
    const int sel  = (quad ^ ((l16 >> 1) & 3)) << 4;   // swizzled 16B slot
    const int aoff = (wr * 128 + l16) * 64 + sel;      // byte off in A units
    const int boff = (wc * 64  + l16) * 64 + sel;      // byte off in B units

    floatx4 acc[8][4] = {};

    const unsigned short* Abase = gA + (size_t)bi * 256 * K2;
    const unsigned short* Bbase = gB + (size_t)bj * 256 * K2;

    // prologue: chunk 0's four units into buffer 0
    stage_unit256(Abase, 0, 0, U[0], tid);
    stage_unit256(Bbase, 0, 0, U[2], tid);
    stage_unit256(Abase, 0, 1, U[4], tid);
    stage_unit256(Bbase, 0, 1, U[6], tid);

    #pragma unroll 1
    for (int kc = 0; kc < 8; ++kc){
        const int d = kc & 1, e = d ^ 1;

        __builtin_amdgcn_s_barrier();            // A: buf[e] readers done
        SBAR0();
        if (kc < 7){
            // batch-issue next chunk (deep DMA queue: 16 ops in flight)
            stage_unit256(Abase, kc + 1, 0, U[0 + e], tid);
            stage_unit256(Bbase, kc + 1, 0, U[2 + e], tid);
            stage_unit256(Abase, kc + 1, 1, U[4 + e], tid);
            stage_unit256(Bbase, kc + 1, 1, U[6 + e], tid);
            SBAR0();
            asm volatile("s_waitcnt vmcnt(8)" ::: "memory");   // chunk kc done
        } else {
            asm volatile("s_waitcnt vmcnt(0)" ::: "memory");   // tail drain
        }
        __builtin_amdgcn_s_barrier();            // B: publish chunk kc
        SBAR0();

        // ---- 6 compute phases, barrier-free ----
        short8 ah[8], bh[4];
        LDA4(U[0 + d], &ah[0], 0); LDB4(U[2 + d], bh);
        __builtin_amdgcn_s_setprio(1); MFQ(&ah[0], bh, 0); __builtin_amdgcn_s_setprio(0);
        SBAR0();
        LDA4(U[0 + d], &ah[4], 4);
        __builtin_amdgcn_s_setprio(1); MFQ(&ah[4], bh, 4); __builtin_amdgcn_s_setprio(0);
        SBAR0();
        {
            short8 al0[4]; LDA4(U[4 + d], al0, 0);
            __builtin_amdgcn_s_setprio(1); MFQ(al0, bh, 0); __builtin_amdgcn_s_setprio(0);
            SBAR0();
        }
        {
            short8 al1[4]; LDA4(U[4 + d], al1, 4);
            __builtin_amdgcn_s_setprio(1); MFQ(al1, bh, 4); __builtin_amdgcn_s_setprio(0);
            SBAR0();
        }
        {
            short8 bl[4]; LDB4(U[6 + d], bl);
            __builtin_amdgcn_s_setprio(1); MFQ(&ah[0], bl, 0); __builtin_amdgcn_s_setprio(0);
            SBAR0();
            __builtin_amdgcn_s_setprio(1); MFQ(&ah[4], bl, 4); __builtin_amdgcn_s_setprio(0);
            SBAR0();
        }
    }

    // ---- fused stats epilogue ----
    // C/D layout (verified m89/m91): col = lane&15, row = quad*4 + reg.
    // acc[mi][nj]: row = wr*128 + mi*16 + quad*4 + r ; col = wc*64 + nj*16 + l16.
    const int rowbase = bi * 256 + wr * 128;
    const int colbase = bj * 256 + wc * 64;

    // row stats: each lane holds 4 cols (nj); reduce across l16 lanes.
    #pragma unroll
    for (int mi = 0; mi < 8; ++mi){
        #pragma unroll
        for (int r = 0; r < 4; ++r){
            const int gi = rowbase + mi * 16 + quad * 4 + r;
            const float dv = g_diag[gi];
            int cnt = 0; float mx = -3.0e38f;
            #pragma unroll
            for (int nj = 0; nj < 4; ++nj){
                const float v  = acc[mi][nj][r];
                const int   gj = colbase + nj * 16 + l16;
                if (gi != gj){                 // exclude diagonal explicitly
                    cnt += (v < dv) ? 1 : 0;
                    mx = fmaxf(mx, v);
                }
            }
            #pragma unroll
            for (int m = 1; m < 16; m <<= 1){
                cnt += __shfl_xor(cnt, m, 64);
                mx   = fmaxf(mx, __shfl_xor(mx, m, 64));
            }
            if (l16 == 0){
                atomicAdd(&g_rowcnt[gi], (unsigned)cnt);
                atomicMax(&g_rowkey[gi], fkey(mx));
            }
        }
    }
    // col stats: each lane holds 32 rows (mi,r) per nj; reduce across quads.
    #pragma unroll
    for (int nj = 0; nj < 4; ++nj){
        const int gj = colbase + nj * 16 + l16;
        const float dv = g_diag[gj];
        int cnt = 0; float mx = -3.0e38f;
        #pragma unroll
        for (int mi = 0; mi < 8; ++mi){
            #pragma unroll
            for (int r = 0; r < 4; ++r){
                const float v  = acc[mi][nj][r];
                const int   gi = rowbase + mi * 16 + quad * 4 + r;
                if (gi != gj){
                    cnt += (v < dv) ? 1 : 0;
                    mx = fmaxf(mx, v);
                }
            }
        }
        #pragma unroll
        for (int m = 16; m < 64; m <<= 1){
            cnt += __shfl_xor(cnt, m, 64);
            mx   = fmaxf(mx, __shfl_xor(mx, m, 64));
        }
        if (quad == 0){
            atomicAdd(&g_colcnt[gj], (unsigned)cnt);
            atomicMax(&g_colkey[gj], fkey(mx));
        }
    }
}

__global__ __launch_bounds__(256) void finalize_kernel(float* __restrict__ out){
    __shared__ double red[256];
    double acc = 0.0;
    #pragma unroll
    for (int it = 0; it < NROWS / 256; ++it){
        const int i = it * 256 + threadIdx.x;
        const float d  = g_diag[i];
        const float cs  = fmaxf(MARGIN_F + kinv(g_rowkey[i]) - d, 0.0f) * (1.0f / (float)(g_rowcnt[i] + 1u));
        const float cim = fmaxf(MARGIN_F + kinv(g_colkey[i]) - d, 0.0f) * (1.0f / (float)(g_colcnt[i] + 1u));
        acc += (double)cs + (double)cim;
    }
    red[threadIdx.x] = acc;
    __syncthreads();
    for (int s2 = 128; s2 > 0; s2 >>= 1){
        if (threadIdx.x < s2) red[threadIdx.x] += red[threadIdx.x + s2];
        __syncthreads();
    }
    if (threadIdx.x == 0) out[0] = (float)red[0];
}

extern "C" void kernel_launch(void* const* d_in, const int* in_sizes, int n_in,
                              void* d_out, int out_size, void* d_ws, size_t ws_size,
                              hipStream_t stream){
    const float* im = (const float*)d_in[0];
    const float* s  = (const float*)d_in[1];
    float* out = (float*)d_out;

    prep_kernel<<<NROWS / 4, 256, 0, stream>>>(im, s);
    gemm_stats_kernel<<<1024, 512, 0, stream>>>();
    finalize_kernel<<<1, 256, 0, stream>>>(out);
}

// Round 8
// 242.142 us; speedup vs baseline: 5.6030x; 1.0450x over previous
//
#include <hip/hip_runtime.h>
#include <stdint.h>

#define NROWS 8192
#define DDIM  256
#define K2    512          // hi|lo shorts per row (size bookkeeping only)
#define BLKSTRIDE 131072   // shorts per 256-row block (16 units x 8192)
#define MARGIN_F 0.2f
#define MFMA16 __builtin_amdgcn_mfma_f32_16x16x32_bf16
#define SBAR0() __builtin_amdgcn_sched_barrier(0)

typedef short  short8  __attribute__((ext_vector_type(8)));
typedef float  floatx4 __attribute__((ext_vector_type(4)));

// Fragment/unit-packed operand layout (written by prep, read by gemm DMA):
//   blk = row>>8 (32 blocks of 256 rows)
//   unit u = kc*2 + hl  (kc = 32-k chunk 0..7, hl = hi/lo), 16 units/blk
//   unit = 16KB CONTIGUOUS, content = exactly the bytes the old scattered
//   stage wrote to LDS (slot swizzle sp = s ^ ((r>>1)&3) baked in at pack
//   time). Staging is then a pure sequential burst: thread t reads
//   unit_base + t*16 (+8KB for the second half) -> every wave-instr = 1KB
//   contiguous, full L2-line utilization, no permuted request stream.
__device__ unsigned short gA[(size_t)NROWS * K2];   // im, unit-packed
__device__ unsigned short gB[(size_t)NROWS * K2];   // s,  unit-packed
__device__ float    g_diag[NROWS];
__device__ unsigned g_rowcnt[NROWS];
__device__ unsigned g_rowkey[NROWS];
__device__ unsigned g_colcnt[NROWS];
__device__ unsigned g_colkey[NROWS];

__device__ __forceinline__ unsigned short f2bf_rne(float x){
    unsigned u = __float_as_uint(x);
    return (unsigned short)((u + 0x7FFFu + ((u >> 16) & 1u)) >> 16);
}
__device__ __forceinline__ float bf2f(unsigned short h){
    return __uint_as_float(((unsigned)h) << 16);
}
// monotone float -> uint key (order-preserving), so atomicMax works on floats
__device__ __forceinline__ unsigned fkey(float f){
    unsigned u = __float_as_uint(f);
    return (u & 0x80000000u) ? ~u : (u | 0x80000000u);
}
__device__ __forceinline__ float kinv(unsigned k){
    unsigned u = (k & 0x80000000u) ? (k ^ 0x80000000u) : ~k;
    return __uint_as_float(u);
}

__device__ __forceinline__ void load_lds16(const unsigned short* gptr, void* lptr){
    __builtin_amdgcn_global_load_lds(
        (const __attribute__((address_space(1))) unsigned int*)(uintptr_t)gptr,
        (__attribute__((address_space(3))) unsigned int*)(unsigned)(uintptr_t)lptr,
        16, 0, 0);
}

// One wave per row: fp32 diag dot, hi/lo bf16 split, unit-packed store.
// Lane covers k = lane*4..lane*4+3: kc = lane>>3, slot s = (lane&7)>>1,
// half = lane&1. Packed addr (shorts) within unit: r*32 + sp*8 + half*4,
// sp = s ^ ((r>>1)&3)  — identical content to what R17's scattered stage
// placed in LDS, so the gemm kernel's LDS image is bit-identical.
__global__ __launch_bounds__(256) void prep_kernel(const float* __restrict__ im,
                                                   const float* __restrict__ s){
    const int w    = threadIdx.x >> 6;
    const int lane = threadIdx.x & 63;
    const int row  = blockIdx.x * 4 + w;

    const float4 a = ((const float4*)(im + (size_t)row * DDIM))[lane];
    const float4 b = ((const float4*)(s  + (size_t)row * DDIM))[lane];

    float dp = a.x*b.x + a.y*b.y + a.z*b.z + a.w*b.w;
    #pragma unroll
    for (int m = 1; m < 64; m <<= 1) dp += __shfl_xor(dp, m, 64);
    if (lane == 0){
        g_diag[row]   = dp;
        g_rowcnt[row] = 0u; g_rowkey[row] = 0u;
        g_colcnt[row] = 0u; g_colkey[row] = 0u;
    }

    float av[4] = {a.x, a.y, a.z, a.w};
    float bv[4] = {b.x, b.y, b.z, b.w};
    unsigned short ah[4], al[4], bh[4], bl[4];
    #pragma unroll
    for (int i = 0; i < 4; ++i){
        ah[i] = f2bf_rne(av[i]); al[i] = f2bf_rne(av[i] - bf2f(ah[i]));
        bh[i] = f2bf_rne(bv[i]); bl[i] = f2bf_rne(bv[i] - bf2f(bh[i]));
    }
    const int blk = row >> 8, r = row & 255;
    const int kc  = lane >> 3;
    const int sp  = (((lane & 7) >> 1) ^ ((r >> 1) & 3));
    const int hf  = (lane & 1) * 4;
    const size_t ub = (size_t)blk * BLKSTRIDE + (size_t)(kc * 2) * 8192
                    + (size_t)r * 32 + sp * 8 + hf;      // hl=0 unit
    *(ushort4*)&gA[ub       ] = make_ushort4(ah[0], ah[1], ah[2], ah[3]);
    *(ushort4*)&gA[ub + 8192] = make_ushort4(al[0], al[1], al[2], al[3]);  // hl=1
    *(ushort4*)&gB[ub       ] = make_ushort4(bh[0], bh[1], bh[2], bh[3]);
    *(ushort4*)&gB[ub + 8192] = make_ushort4(bl[0], bl[1], bl[2], bl[3]);
}

// Stage one 16KB unit — now a PURE SEQUENTIAL burst (unit-packed source).
// LDS image identical to R13/R15/R17's (verified index algebra; absmax 0).
__device__ __forceinline__ void stage_unit256(const unsigned short* __restrict__ Obase,
                                              int c, int hl, unsigned short* sb, int tid){
    const unsigned short* u = Obase + (size_t)(c * 2 + hl) * 8192;
    load_lds16(u + (size_t)tid * 8,        (char*)sb + tid * 16);
    load_lds16(u + 4096 + (size_t)tid * 8, (char*)sb + 8192 + tid * 16);
}

// ---- compute helpers (identical math/order to R15/R17) ----
#define MFQ(A4, B4, MB) { \
    _Pragma("unroll") \
    for (int i_ = 0; i_ < 4; ++i_){ \
        _Pragma("unroll") \
        for (int nj_ = 0; nj_ < 4; ++nj_) \
            acc[(MB) + i_][nj_] = MFMA16((A4)[i_], (B4)[nj_], acc[(MB) + i_][nj_], 0, 0, 0); \
    } }
#define LDA4(U_, F_, MB) { \
    _Pragma("unroll") \
    for (int i_ = 0; i_ < 4; ++i_) \
        (F_)[i_] = *(const short8*)((const char*)(U_) + aoff + ((MB) + i_) * 1024); }
#define LDB4(U_, F_) { \
    _Pragma("unroll") \
    for (int nj_ = 0; nj_ < 4; ++nj_) \
        (F_)[nj_] = *(const short8*)((const char*)(U_) + boff + nj_ * 1024); }

// 256x256 tile, 8 waves (2Mx4N, 128x64/wave), 16x16x32 bf16, 3-pass hi/lo.
// R18 vs R17: ONLY the DMA source layout changes (unit-packed contiguous vs
// 64B-fragment scatter with slot permutation). Seven structures have pinned
// at 184-203us / 22-24% MfmaUtil with staging delivery stuck at 4.7-9
// B/cyc/CU, while m97/m201 sustain 21.8-31 B/cyc/CU through the SAME
// global_load_lds instruction -> the request stream (half-line 64B granules,
// permuted slots) is the last untested difference on the staging path.
// Skeleton unchanged from R17: 2 barriers/chunk, batch-issued chunk staging,
// vmcnt(8) targeting data issued a full chunk earlier, 6 barrier-free
// compute phases. Accumulation order unchanged => absmax 0.
__global__ __launch_bounds__(512, 2) void gemm_stats_kernel(){
    __shared__ unsigned short U[8][256 * 32];   // [0+d]=Ah, [2+d]=Bh, [4+d]=Al, [6+d]=Bl

    const int tid = threadIdx.x;
    const int bid = blockIdx.x;
    // bid[2:0]->XCD band of bi, bid[4:3]->bi within band, bid[9:5]->bj
    const int bi  = (bid & 7) * 4 + ((bid >> 3) & 3);
    const int bj  = bid >> 5;

    const int w    = tid >> 6, lane = tid & 63;
    const int quad = lane >> 4, l16 = lane & 15;
    const int wr   = w >> 2,   wc  = w & 3;
    const int sel  = (quad ^ ((l16 >> 1) & 3)) << 4;   // swizzled 16B slot
    const int aoff = (wr * 128 + l16) * 64 + sel;      // byte off in A units
    const int boff = (wc * 64  + l16) * 64 + sel;      // byte off in B units

    floatx4 acc[8][4] = {};

    const unsigned short* Abase = gA + (size_t)bi * BLKSTRIDE;
    const unsigned short* Bbase = gB + (size_t)bj * BLKSTRIDE;

    // prologue: chunk 0's four units into buffer 0
    stage_unit256(Abase, 0, 0, U[0], tid);
    stage_unit256(Bbase, 0, 0, U[2], tid);
    stage_unit256(Abase, 0, 1, U[4], tid);
    stage_unit256(Bbase, 0, 1, U[6], tid);

    #pragma unroll 1
    for (int kc = 0; kc < 8; ++kc){
        const int d = kc & 1, e = d ^ 1;

        __builtin_amdgcn_s_barrier();            // A: buf[e] readers done
        SBAR0();
        if (kc < 7){
            // batch-issue next chunk (deep DMA queue: 16 ops in flight)
            stage_unit256(Abase, kc + 1, 0, U[0 + e], tid);
            stage_unit256(Bbase, kc + 1, 0, U[2 + e], tid);
            stage_unit256(Abase, kc + 1, 1, U[4 + e], tid);
            stage_unit256(Bbase, kc + 1, 1, U[6 + e], tid);
            SBAR0();
            asm volatile("s_waitcnt vmcnt(8)" ::: "memory");   // chunk kc done
        } else {
            asm volatile("s_waitcnt vmcnt(0)" ::: "memory");   // tail drain
        }
        __builtin_amdgcn_s_barrier();            // B: publish chunk kc
        SBAR0();

        // ---- 6 compute phases, barrier-free ----
        short8 ah[8], bh[4];
        LDA4(U[0 + d], &ah[0], 0); LDB4(U[2 + d], bh);
        __builtin_amdgcn_s_setprio(1); MFQ(&ah[0], bh, 0); __builtin_amdgcn_s_setprio(0);
        SBAR0();
        LDA4(U[0 + d], &ah[4], 4);
        __builtin_amdgcn_s_setprio(1); MFQ(&ah[4], bh, 4); __builtin_amdgcn_s_setprio(0);
        SBAR0();
        {
            short8 al0[4]; LDA4(U[4 + d], al0, 0);
            __builtin_amdgcn_s_setprio(1); MFQ(al0, bh, 0); __builtin_amdgcn_s_setprio(0);
            SBAR0();
        }
        {
            short8 al1[4]; LDA4(U[4 + d], al1, 4);
            __builtin_amdgcn_s_setprio(1); MFQ(al1, bh, 4); __builtin_amdgcn_s_setprio(0);
            SBAR0();
        }
        {
            short8 bl[4]; LDB4(U[6 + d], bl);
            __builtin_amdgcn_s_setprio(1); MFQ(&ah[0], bl, 0); __builtin_amdgcn_s_setprio(0);
            SBAR0();
            __builtin_amdgcn_s_setprio(1); MFQ(&ah[4], bl, 4); __builtin_amdgcn_s_setprio(0);
            SBAR0();
        }
    }

    // ---- fused stats epilogue ----
    // C/D layout (verified m89/m91): col = lane&15, row = quad*4 + reg.
    // acc[mi][nj]: row = wr*128 + mi*16 + quad*4 + r ; col = wc*64 + nj*16 + l16.
    const int rowbase = bi * 256 + wr * 128;
    const int colbase = bj * 256 + wc * 64;

    // row stats: each lane holds 4 cols (nj); reduce across l16 lanes.
    #pragma unroll
    for (int mi = 0; mi < 8; ++mi){
        #pragma unroll
        for (int r = 0; r < 4; ++r){
            const int gi = rowbase + mi * 16 + quad * 4 + r;
            const float dv = g_diag[gi];
            int cnt = 0; float mx = -3.0e38f;
            #pragma unroll
            for (int nj = 0; nj < 4; ++nj){
                const float v  = acc[mi][nj][r];
                const int   gj = colbase + nj * 16 + l16;
                if (gi != gj){                 // exclude diagonal explicitly
                    cnt += (v < dv) ? 1 : 0;
                    mx = fmaxf(mx, v);
                }
            }
            #pragma unroll
            for (int m = 1; m < 16; m <<= 1){
                cnt += __shfl_xor(cnt, m, 64);
                mx   = fmaxf(mx, __shfl_xor(mx, m, 64));
            }
            if (l16 == 0){
                atomicAdd(&g_rowcnt[gi], (unsigned)cnt);
                atomicMax(&g_rowkey[gi], fkey(mx));
            }
        }
    }
    // col stats: each lane holds 32 rows (mi,r) per nj; reduce across quads.
    #pragma unroll
    for (int nj = 0; nj < 4; ++nj){
        const int gj = colbase + nj * 16 + l16;
        const float dv = g_diag[gj];
        int cnt = 0; float mx = -3.0e38f;
        #pragma unroll
        for (int mi = 0; mi < 8; ++mi){
            #pragma unroll
            for (int r = 0; r < 4; ++r){
                const float v  = acc[mi][nj][r];
                const int   gi = rowbase + mi * 16 + quad * 4 + r;
                if (gi != gj){
                    cnt += (v < dv) ? 1 : 0;
                    mx = fmaxf(mx, v);
                }
            }
        }
        #pragma unroll
        for (int m = 16; m < 64; m <<= 1){
            cnt += __shfl_xor(cnt, m, 64);
            mx   = fmaxf(mx, __shfl_xor(mx, m, 64));
        }
        if (quad == 0){
            atomicAdd(&g_colcnt[gj], (unsigned)cnt);
            atomicMax(&g_colkey[gj], fkey(mx));
        }
    }
}

__global__ __launch_bounds__(256) void finalize_kernel(float* __restrict__ out){
    __shared__ double red[256];
    double acc = 0.0;
    #pragma unroll
    for (int it = 0; it < NROWS / 256; ++it){
        const int i = it * 256 + threadIdx.x;
        const float d  = g_diag[i];
        const float cs  = fmaxf(MARGIN_F + kinv(g_rowkey[i]) - d, 0.0f) * (1.0f / (float)(g_rowcnt[i] + 1u));
        const float cim = fmaxf(MARGIN_F + kinv(g_colkey[i]) - d, 0.0f) * (1.0f / (float)(g_colcnt[i] + 1u));
        acc += (double)cs + (double)cim;
    }
    red[threadIdx.x] = acc;
    __syncthreads();
    for (int s2 = 128; s2 > 0; s2 >>= 1){
        if (threadIdx.x < s2) red[threadIdx.x] += red[threadIdx.x + s2];
        __syncthreads();
    }
    if (threadIdx.x == 0) out[0] = (float)red[0];
}

extern "C" void kernel_launch(void* const* d_in, const int* in_sizes, int n_in,
                              void* d_out, int out_size, void* d_ws, size_t ws_size,
                              hipStream_t stream){
    const float* im = (const float*)d_in[0];
    const float* s  = (const float*)d_in[1];
    float* out = (float*)d_out;

    prep_kernel<<<NROWS / 4, 256, 0, stream>>>(im, s);
    gemm_stats_kernel<<<1024, 512, 0, stream>>>();
    finalize_kernel<<<1, 256, 0, stream>>>(out);
}